// Round 4
// baseline (271.584 us; speedup 1.0000x reference)
//
#include <hip/hip_runtime.h>
#include <math.h>

#define NTOK 65536
#define CDIM 256
#define DDIM 16
#define KCOD 4096
#define HWSZ 4096

#define KSPLIT 16
#define CPS (KCOD / KSPLIT)   // 256 codes per split-block
#define TPT 4                 // tokens per thread in kscan (fits VGPRs!)
#define TBLK (256 * TPT)      // 1024 tokens per kscan block

// ---- ws layout (float offsets) ----
#define WS_ENORM 0                         // [65536] normalized codebook
#define WS_ENN   (WS_ENORM + KCOD*DDIM)    // [4096]  sum(e_norm^2)
#define WS_WDT   (WS_ENN + KCOD)           // [4096]  w_down transposed [c][d]
#define WS_ZN    (WS_WDT + CDIM*DDIM)      // [1048576] z_norm [N,16]
#define WS_BCS   (WS_ZN + NTOK*DDIM)       // [4096]  batch_cluster_size
#define WS_BES   (WS_BCS + KCOD)           // [65536] batch_embed_sum
#define WS_SCAL  (WS_BES + KCOD*DDIM)      // [8] 0=loss_sum 1=n_sum 2=ent_sum
#define WS_PACK  (WS_SCAL + 8)             // [65536 x u64] packed (score,idx)
// WS_PACK float-offset 1191944 -> byte 4767776, 8B aligned.

// ---- out layout (float offsets) ----
#define OFS_ZQ   0
#define OFS_LOSS 16777216
#define OFS_IDX  16777217
#define OFS_ENT  16842753
#define OFS_NE   16842754
#define OFS_NCS  16908290
#define OFS_NEA  16912386

// ============ normalize codebook + transpose w_down ============
__global__ __launch_bounds__(256) void knorm_kernel(const float* __restrict__ emb,
                                                    const float* __restrict__ w_down,
                                                    float* __restrict__ ws) {
  int k = blockIdx.x * 256 + threadIdx.x;
  const float4* src = (const float4*)emb + (size_t)k * 4;
  float4 t0 = src[0], t1 = src[1], t2 = src[2], t3 = src[3];
  float e[16] = {t0.x,t0.y,t0.z,t0.w, t1.x,t1.y,t1.z,t1.w,
                 t2.x,t2.y,t2.z,t2.w, t3.x,t3.y,t3.z,t3.w};
  float ss = 0.f;
  #pragma unroll
  for (int d = 0; d < 16; ++d) ss += e[d] * e[d];
  float dn = fmaxf(sqrtf(ss), 1e-12f);
  #pragma unroll
  for (int d = 0; d < 16; ++d) e[d] = e[d] / dn;
  float s2 = 0.f;
  #pragma unroll
  for (int d = 0; d < 16; ++d) s2 += e[d] * e[d];
  float4* dst = (float4*)(ws + WS_ENORM) + (size_t)k * 4;
  dst[0] = make_float4(e[0],e[1],e[2],e[3]);
  dst[1] = make_float4(e[4],e[5],e[6],e[7]);
  dst[2] = make_float4(e[8],e[9],e[10],e[11]);
  dst[3] = make_float4(e[12],e[13],e[14],e[15]);
  ws[WS_ENN + k] = s2;
  // transpose w_down [d][c] -> wdt [c][d]  (4096 elements, one per thread)
  ws[WS_WDT + k] = w_down[(k & 15) * 256 + (k >> 4)];
}

// ============ down-proj + L2-normalize -> ws ZN ============
// weights read via wave-uniform loads (scalar path) - no LDS pipe pressure
__global__ __launch_bounds__(256) void kdown_kernel(const float* __restrict__ z,
                                                    const float* __restrict__ wdt,
                                                    const float* __restrict__ b_down,
                                                    float* __restrict__ znp) {
  const int tid = threadIdx.x;
  const int n = blockIdx.x * 256 + tid;
  const int b = n >> 12;
  const int hw = n & 4095;

  const float* zp = z + (size_t)b * (CDIM * HWSZ) + hw;
  float acc[16];
  #pragma unroll
  for (int d = 0; d < 16; ++d) acc[d] = 0.f;
  #pragma unroll 8
  for (int c = 0; c < CDIM; ++c) {
    float zv = zp[(size_t)c * HWSZ];
    const float4* wr = (const float4*)(wdt + c * 16); // uniform address
    float4 w0 = wr[0], w1 = wr[1], w2 = wr[2], w3 = wr[3];
    acc[0]  = fmaf(zv, w0.x, acc[0]);  acc[1]  = fmaf(zv, w0.y, acc[1]);
    acc[2]  = fmaf(zv, w0.z, acc[2]);  acc[3]  = fmaf(zv, w0.w, acc[3]);
    acc[4]  = fmaf(zv, w1.x, acc[4]);  acc[5]  = fmaf(zv, w1.y, acc[5]);
    acc[6]  = fmaf(zv, w1.z, acc[6]);  acc[7]  = fmaf(zv, w1.w, acc[7]);
    acc[8]  = fmaf(zv, w2.x, acc[8]);  acc[9]  = fmaf(zv, w2.y, acc[9]);
    acc[10] = fmaf(zv, w2.z, acc[10]); acc[11] = fmaf(zv, w2.w, acc[11]);
    acc[12] = fmaf(zv, w3.x, acc[12]); acc[13] = fmaf(zv, w3.y, acc[13]);
    acc[14] = fmaf(zv, w3.z, acc[14]); acc[15] = fmaf(zv, w3.w, acc[15]);
  }
  #pragma unroll
  for (int d = 0; d < 16; ++d) acc[d] = acc[d] + b_down[d];
  float ss = 0.f;
  #pragma unroll
  for (int d = 0; d < 16; ++d) ss += acc[d] * acc[d];
  float dn = fmaxf(sqrtf(ss), 1e-12f);
  float zn[16];
  #pragma unroll
  for (int d = 0; d < 16; ++d) zn[d] = acc[d] / dn;

  float4* op = (float4*)znp + (size_t)n * 4;
  op[0] = make_float4(zn[0],zn[1],zn[2],zn[3]);
  op[1] = make_float4(zn[4],zn[5],zn[6],zn[7]);
  op[2] = make_float4(zn[8],zn[9],zn[10],zn[11]);
  op[3] = make_float4(zn[12],zn[13],zn[14],zn[15]);
}

// ============ argmin scan: K split 16 ways, 4 tokens/thread ============
// score = enn - 2*dot  (== d2 - znn; znn constant per token -> argmin-equal)
__global__ __launch_bounds__(256, 4) void kscan_kernel(const float* __restrict__ enorm,
                                                       const float* __restrict__ ennp,
                                                       const float* __restrict__ znp,
                                                       unsigned long long* __restrict__ packp) {
  __shared__ float ecache[CPS * DDIM]; // 16 KB
  __shared__ float encache[CPS];       // 1 KB

  const int tid = threadIdx.x;
  const int kbase = blockIdx.y * CPS;

  {
    const float4* s4 = (const float4*)(enorm + (size_t)kbase * 16);
    float4* d4 = (float4*)ecache;
    #pragma unroll
    for (int i = 0; i < 4; ++i) d4[tid + i * 256] = s4[tid + i * 256];
    encache[tid] = ennp[kbase + tid];
  }
  __syncthreads();

  // load 4 tokens' z_norm, pre-scaled by -2
  float nz[TPT][16];
  float best[TPT];
  int bidx[TPT];
  const int tokbase = blockIdx.x * TBLK + tid;
  {
    const float4* zp = (const float4*)znp;
    #pragma unroll
    for (int p = 0; p < TPT; ++p) {
      int tok = tokbase + p * 256;
      float4 a0 = zp[(size_t)tok * 4 + 0];
      float4 a1 = zp[(size_t)tok * 4 + 1];
      float4 a2 = zp[(size_t)tok * 4 + 2];
      float4 a3 = zp[(size_t)tok * 4 + 3];
      nz[p][0]=-2.f*a0.x; nz[p][1]=-2.f*a0.y; nz[p][2]=-2.f*a0.z; nz[p][3]=-2.f*a0.w;
      nz[p][4]=-2.f*a1.x; nz[p][5]=-2.f*a1.y; nz[p][6]=-2.f*a1.z; nz[p][7]=-2.f*a1.w;
      nz[p][8]=-2.f*a2.x; nz[p][9]=-2.f*a2.y; nz[p][10]=-2.f*a2.z; nz[p][11]=-2.f*a2.w;
      nz[p][12]=-2.f*a3.x; nz[p][13]=-2.f*a3.y; nz[p][14]=-2.f*a3.z; nz[p][15]=-2.f*a3.w;
      best[p] = 3.4e38f;
      bidx[p] = 0;
    }
  }

  #pragma unroll 2
  for (int j = 0; j < CPS; ++j) {
    const float4* e4 = (const float4*)(ecache + j * 16);
    float4 c0 = e4[0], c1 = e4[1], c2 = e4[2], c3 = e4[3];
    float en = encache[j];
    #pragma unroll
    for (int p = 0; p < TPT; ++p) {
      float d = en;
      d = fmaf(nz[p][0],  c0.x, d); d = fmaf(nz[p][1],  c0.y, d);
      d = fmaf(nz[p][2],  c0.z, d); d = fmaf(nz[p][3],  c0.w, d);
      d = fmaf(nz[p][4],  c1.x, d); d = fmaf(nz[p][5],  c1.y, d);
      d = fmaf(nz[p][6],  c1.z, d); d = fmaf(nz[p][7],  c1.w, d);
      d = fmaf(nz[p][8],  c2.x, d); d = fmaf(nz[p][9],  c2.y, d);
      d = fmaf(nz[p][10], c2.z, d); d = fmaf(nz[p][11], c2.w, d);
      d = fmaf(nz[p][12], c3.x, d); d = fmaf(nz[p][13], c3.y, d);
      d = fmaf(nz[p][14], c3.z, d); d = fmaf(nz[p][15], c3.w, d);
      if (d < best[p]) { best[p] = d; bidx[p] = j; }
    }
  }

  // merge across splits: packed (ordered-score, idx) atomicMin -> exact
  // lowest-index tie-break like jnp.argmin
  #pragma unroll
  for (int p = 0; p < TPT; ++p) {
    int tok = tokbase + p * 256;
    unsigned u = __float_as_uint(best[p]);
    u = (u & 0x80000000u) ? ~u : (u | 0x80000000u);
    unsigned long long key =
        ((unsigned long long)u << 32) | (unsigned)(kbase + bidx[p]);
    atomicMin(packp + tok, key);
  }
}

// ============ merge + scatter + loss + fused up-projection ============
__global__ __launch_bounds__(256) void kfinal_kernel(const float* __restrict__ w_up,
                                                     const float* __restrict__ b_up,
                                                     const float* __restrict__ enorm,
                                                     const float* __restrict__ znp,
                                                     const unsigned long long* __restrict__ packp,
                                                     float* __restrict__ wsacc,
                                                     float* __restrict__ out) {
  const int tid = threadIdx.x;
  const int n = blockIdx.x * 256 + tid;
  const int bidx = (int)(unsigned)(packp[n] & 0xFFFFFFFFull);

  float zn[16];
  {
    const float4* zp = (const float4*)znp + (size_t)n * 4;
    float4 a0 = zp[0], a1 = zp[1], a2 = zp[2], a3 = zp[3];
    zn[0]=a0.x; zn[1]=a0.y; zn[2]=a0.z; zn[3]=a0.w;
    zn[4]=a1.x; zn[5]=a1.y; zn[6]=a1.z; zn[7]=a1.w;
    zn[8]=a2.x; zn[9]=a2.y; zn[10]=a2.z; zn[11]=a2.w;
    zn[12]=a3.x; zn[13]=a3.y; zn[14]=a3.z; zn[15]=a3.w;
  }
  float zq[16];
  {
    const float4* eb = (const float4*)enorm + (size_t)bidx * 4;
    float4 q0 = eb[0], q1 = eb[1], q2 = eb[2], q3 = eb[3];
    zq[0]=q0.x; zq[1]=q0.y; zq[2]=q0.z; zq[3]=q0.w;
    zq[4]=q1.x; zq[5]=q1.y; zq[6]=q1.z; zq[7]=q1.w;
    zq[8]=q2.x; zq[9]=q2.y; zq[10]=q2.z; zq[11]=q2.w;
    zq[12]=q3.x; zq[13]=q3.y; zq[14]=q3.z; zq[15]=q3.w;
  }

  out[OFS_IDX + n] = (float)bidx;

  float ls = 0.f;
  #pragma unroll
  for (int d = 0; d < 16; ++d) { float df = zn[d] - zq[d]; ls = fmaf(df, df, ls); }

  atomicAdd(wsacc + WS_BCS - WS_BCS + bidx, 1.0f); // wsacc points at WS_BCS
  #pragma unroll
  for (int d = 0; d < 16; ++d)
    atomicAdd(wsacc + KCOD + (size_t)bidx * 16 + d, zn[d]); // BES follows BCS

  #pragma unroll
  for (int off = 32; off > 0; off >>= 1) ls += __shfl_down(ls, off, 64);
  if ((tid & 63) == 0) atomicAdd(wsacc + KCOD + KCOD * DDIM + 0, ls); // SCAL[0]

  // straight-through value: ql = zn + (zq - zn), same fp ops as the ref
  float ql[16];
  #pragma unroll
  for (int d = 0; d < 16; ++d) ql[d] = zn[d] + (zq[d] - zn[d]);

  const int b = n >> 12, hw = n & 4095;
  float* op = out + OFS_ZQ + (size_t)b * (CDIM * HWSZ) + hw;
  #pragma unroll 8
  for (int c = 0; c < CDIM; ++c) {
    const float4* wr = (const float4*)(w_up + c * 16); // uniform address
    float4 w0 = wr[0], w1 = wr[1], w2 = wr[2], w3 = wr[3];
    float a = 0.f;
    a = fmaf(ql[0],  w0.x, a); a = fmaf(ql[1],  w0.y, a);
    a = fmaf(ql[2],  w0.z, a); a = fmaf(ql[3],  w0.w, a);
    a = fmaf(ql[4],  w1.x, a); a = fmaf(ql[5],  w1.y, a);
    a = fmaf(ql[6],  w1.z, a); a = fmaf(ql[7],  w1.w, a);
    a = fmaf(ql[8],  w2.x, a); a = fmaf(ql[9],  w2.y, a);
    a = fmaf(ql[10], w2.z, a); a = fmaf(ql[11], w2.w, a);
    a = fmaf(ql[12], w3.x, a); a = fmaf(ql[13], w3.y, a);
    a = fmaf(ql[14], w3.z, a); a = fmaf(ql[15], w3.w, a);
    a = a + b_up[c];
    op[(size_t)c * HWSZ] = a;
  }
}

// ============ EMA buffers + partial sums (n, entropy) ============
__global__ __launch_bounds__(256) void kema_kernel(const float* __restrict__ cluster_size,
                                                   const float* __restrict__ embed_avg,
                                                   float* __restrict__ ws,
                                                   float* __restrict__ out) {
  const float DEC = 0.99f;
  const float OMD = (float)(1.0 - 0.99);
  const int k = blockIdx.x * 256 + threadIdx.x;
  float bcsv = ws[WS_BCS + k];
  float ncs = cluster_size[k] * DEC + OMD * bcsv;
  out[OFS_NCS + k] = ncs;
  #pragma unroll
  for (int d = 0; d < 16; ++d) {
    float nea = embed_avg[(size_t)k * 16 + d] * DEC + OMD * ws[WS_BES + (size_t)k * 16 + d];
    out[OFS_NEA + (size_t)k * 16 + d] = nea;
  }
  // sum(bcs) == 65536 exactly (integer-valued fp32)
  float p = bcsv / 65536.0f;
  float et = -p * logf(p + 1e-8f);

  __shared__ float r1[4], r2[4];
  float v1 = ncs, v2 = et;
  #pragma unroll
  for (int off = 32; off > 0; off >>= 1) {
    v1 += __shfl_down(v1, off, 64);
    v2 += __shfl_down(v2, off, 64);
  }
  int lane = threadIdx.x & 63, w = threadIdx.x >> 6;
  if (lane == 0) { r1[w] = v1; r2[w] = v2; }
  __syncthreads();
  if (threadIdx.x == 0) {
    atomicAdd(ws + WS_SCAL + 1, (r1[0] + r1[1]) + (r1[2] + r1[3]));
    atomicAdd(ws + WS_SCAL + 2, (r2[0] + r2[1]) + (r2[2] + r2[3]));
  }
}

// ============ new_embedding + scalar outputs ============
__global__ __launch_bounds__(256) void kemb_kernel(const float* __restrict__ ws,
                                                   float* __restrict__ out) {
  const float KEPS = (float)(4096.0 * 1e-5);
  const int k = blockIdx.x * 256 + threadIdx.x;
  float n = ws[WS_SCAL + 1];
  float ncs = out[OFS_NCS + k];
  float cs = (ncs + 1e-5f) / (n + KEPS) * n;
  #pragma unroll
  for (int d = 0; d < 16; ++d)
    out[OFS_NE + (size_t)k * 16 + d] = out[OFS_NEA + (size_t)k * 16 + d] / cs;
  if (k == 0) {
    out[OFS_LOSS] = 0.25f * (ws[WS_SCAL + 0] / 1048576.0f);
    out[OFS_ENT]  = (float)8.317766166719343 - ws[WS_SCAL + 2];
  }
}

extern "C" void kernel_launch(void* const* d_in, const int* in_sizes, int n_in,
                              void* d_out, int out_size, void* d_ws, size_t ws_size,
                              hipStream_t stream) {
  const float* z        = (const float*)d_in[0];
  const float* w_down   = (const float*)d_in[1];
  const float* b_down   = (const float*)d_in[2];
  const float* w_up     = (const float*)d_in[3];
  const float* b_up     = (const float*)d_in[4];
  const float* emb      = (const float*)d_in[5];
  const float* csz      = (const float*)d_in[6];
  const float* eavg     = (const float*)d_in[7];
  float* out = (float*)d_out;
  float* ws  = (float*)d_ws;

  // zero accumulators (bcs+bes+scal); init packed argmin keys to +inf
  hipMemsetAsync(ws + WS_BCS, 0, (size_t)(KCOD + KCOD*DDIM + 8) * sizeof(float), stream);
  hipMemsetAsync(ws + WS_PACK, 0xFF, (size_t)NTOK * 8, stream);

  knorm_kernel<<<KCOD / 256, 256, 0, stream>>>(emb, w_down, ws);
  kdown_kernel<<<NTOK / 256, 256, 0, stream>>>(z, ws + WS_WDT, b_down, ws + WS_ZN);
  kscan_kernel<<<dim3(NTOK / TBLK, KSPLIT), 256, 0, stream>>>(
      ws + WS_ENORM, ws + WS_ENN, ws + WS_ZN,
      (unsigned long long*)(ws + WS_PACK));
  kfinal_kernel<<<NTOK / 256, 256, 0, stream>>>(
      w_up, b_up, ws + WS_ENORM, ws + WS_ZN,
      (const unsigned long long*)(ws + WS_PACK), ws + WS_BCS, out);
  kema_kernel<<<KCOD / 256, 256, 0, stream>>>(csz, eavg, ws, out);
  kemb_kernel<<<KCOD / 256, 256, 0, stream>>>(ws, out);
}

// Round 5
// 254.550 us; speedup vs baseline: 1.0669x; 1.0669x over previous
//
#include <hip/hip_runtime.h>
#include <math.h>

#define NTOK 65536
#define CDIM 256
#define DDIM 16
#define KCOD 4096
#define HWSZ 4096

#define KSPLIT 16
#define CPS (KCOD / KSPLIT)   // 256 codes per split-block
#define TPT 8                 // tokens per thread in kscan
#define TBLK (256 * TPT)      // 2048 tokens per kscan block

// ---- ws layout (float offsets) ----
#define WS_ENORM 0                         // [65536] normalized codebook
#define WS_ENN   (WS_ENORM + KCOD*DDIM)    // [4096]  sum(e_norm^2)
#define WS_WDT   (WS_ENN + KCOD)           // [4096]  w_down transposed [c][d]
#define WS_ZN    (WS_WDT + CDIM*DDIM)      // [1048576] z_norm [N,16]
#define WS_BCS   (WS_ZN + NTOK*DDIM)       // [4096]  batch_cluster_size
#define WS_BES   (WS_BCS + KCOD)           // [65536] batch_embed_sum
#define WS_SCAL  (WS_BES + KCOD*DDIM)      // [8] 0=loss_sum 1=n_sum 2=ent_sum
#define WS_PACK  (WS_SCAL + 8)             // [65536 x u64] packed (score,idx)

// ---- out layout (float offsets) ----
#define OFS_ZQ   0
#define OFS_LOSS 16777216
#define OFS_IDX  16777217
#define OFS_ENT  16842753
#define OFS_NE   16842754
#define OFS_NCS  16908290
#define OFS_NEA  16912386

// ============ normalize codebook + transpose w_down ============
__global__ __launch_bounds__(256) void knorm_kernel(const float* __restrict__ emb,
                                                    const float* __restrict__ w_down,
                                                    float* __restrict__ ws) {
  int k = blockIdx.x * 256 + threadIdx.x;
  const float4* src = (const float4*)emb + (size_t)k * 4;
  float4 t0 = src[0], t1 = src[1], t2 = src[2], t3 = src[3];
  float e[16] = {t0.x,t0.y,t0.z,t0.w, t1.x,t1.y,t1.z,t1.w,
                 t2.x,t2.y,t2.z,t2.w, t3.x,t3.y,t3.z,t3.w};
  float ss = 0.f;
  #pragma unroll
  for (int d = 0; d < 16; ++d) ss += e[d] * e[d];
  float dn = fmaxf(sqrtf(ss), 1e-12f);
  #pragma unroll
  for (int d = 0; d < 16; ++d) e[d] = e[d] / dn;
  float s2 = 0.f;
  #pragma unroll
  for (int d = 0; d < 16; ++d) s2 += e[d] * e[d];
  float4* dst = (float4*)(ws + WS_ENORM) + (size_t)k * 4;
  dst[0] = make_float4(e[0],e[1],e[2],e[3]);
  dst[1] = make_float4(e[4],e[5],e[6],e[7]);
  dst[2] = make_float4(e[8],e[9],e[10],e[11]);
  dst[3] = make_float4(e[12],e[13],e[14],e[15]);
  ws[WS_ENN + k] = s2;
  // transpose w_down [d][c] -> wdt [c][d]
  ws[WS_WDT + k] = w_down[(k & 15) * 256 + (k >> 4)];
}

// ============ down-proj + L2-normalize, 2 tokens/thread ============
__global__ __launch_bounds__(128, 2) void kdown_kernel(const float* __restrict__ z,
                                                       const float* __restrict__ wdt,
                                                       const float* __restrict__ b_down,
                                                       float* __restrict__ znp) {
  __shared__ float wdT[CDIM * DDIM]; // 16 KB, [c][d]
  const int tid = threadIdx.x;
  {
    const float4* s4 = (const float4*)wdt;
    float4* d4 = (float4*)wdT;
    #pragma unroll
    for (int i = 0; i < 8; ++i) d4[tid + i * 128] = s4[tid + i * 128];
  }
  float bd[16];
  {
    const float4* bp = (const float4*)b_down;
    float4 b0 = bp[0], b1 = bp[1], b2 = bp[2], b3 = bp[3];
    bd[0]=b0.x; bd[1]=b0.y; bd[2]=b0.z; bd[3]=b0.w;
    bd[4]=b1.x; bd[5]=b1.y; bd[6]=b1.z; bd[7]=b1.w;
    bd[8]=b2.x; bd[9]=b2.y; bd[10]=b2.z; bd[11]=b2.w;
    bd[12]=b3.x; bd[13]=b3.y; bd[14]=b3.z; bd[15]=b3.w;
  }
  __syncthreads();

  const int n0 = blockIdx.x * 256 + tid; // second token = n0 + 128 (same b)
  const int b = n0 >> 12;
  const int hw = n0 & 4095;
  const float* zp = z + (size_t)b * (CDIM * HWSZ) + hw;

  float a0[16], a1[16];
  #pragma unroll
  for (int d = 0; d < 16; ++d) { a0[d] = 0.f; a1[d] = 0.f; }

  #pragma unroll 16
  for (int c = 0; c < CDIM; ++c) {
    float zv0 = zp[(size_t)c * HWSZ];
    float zv1 = zp[(size_t)c * HWSZ + 128];
    const float4* wr = (const float4*)(wdT + c * 16);
    float4 w0 = wr[0], w1 = wr[1], w2 = wr[2], w3 = wr[3];
    a0[0]  = fmaf(zv0, w0.x, a0[0]);  a1[0]  = fmaf(zv1, w0.x, a1[0]);
    a0[1]  = fmaf(zv0, w0.y, a0[1]);  a1[1]  = fmaf(zv1, w0.y, a1[1]);
    a0[2]  = fmaf(zv0, w0.z, a0[2]);  a1[2]  = fmaf(zv1, w0.z, a1[2]);
    a0[3]  = fmaf(zv0, w0.w, a0[3]);  a1[3]  = fmaf(zv1, w0.w, a1[3]);
    a0[4]  = fmaf(zv0, w1.x, a0[4]);  a1[4]  = fmaf(zv1, w1.x, a1[4]);
    a0[5]  = fmaf(zv0, w1.y, a0[5]);  a1[5]  = fmaf(zv1, w1.y, a1[5]);
    a0[6]  = fmaf(zv0, w1.z, a0[6]);  a1[6]  = fmaf(zv1, w1.z, a1[6]);
    a0[7]  = fmaf(zv0, w1.w, a0[7]);  a1[7]  = fmaf(zv1, w1.w, a1[7]);
    a0[8]  = fmaf(zv0, w2.x, a0[8]);  a1[8]  = fmaf(zv1, w2.x, a1[8]);
    a0[9]  = fmaf(zv0, w2.y, a0[9]);  a1[9]  = fmaf(zv1, w2.y, a1[9]);
    a0[10] = fmaf(zv0, w2.z, a0[10]); a1[10] = fmaf(zv1, w2.z, a1[10]);
    a0[11] = fmaf(zv0, w2.w, a0[11]); a1[11] = fmaf(zv1, w2.w, a1[11]);
    a0[12] = fmaf(zv0, w3.x, a0[12]); a1[12] = fmaf(zv1, w3.x, a1[12]);
    a0[13] = fmaf(zv0, w3.y, a0[13]); a1[13] = fmaf(zv1, w3.y, a1[13]);
    a0[14] = fmaf(zv0, w3.z, a0[14]); a1[14] = fmaf(zv1, w3.z, a1[14]);
    a0[15] = fmaf(zv0, w3.w, a0[15]); a1[15] = fmaf(zv1, w3.w, a1[15]);
  }

  #pragma unroll
  for (int d = 0; d < 16; ++d) { a0[d] += bd[d]; a1[d] += bd[d]; }
  float s0 = 0.f, s1 = 0.f;
  #pragma unroll
  for (int d = 0; d < 16; ++d) { s0 += a0[d] * a0[d]; s1 += a1[d] * a1[d]; }
  float dn0 = fmaxf(sqrtf(s0), 1e-12f);
  float dn1 = fmaxf(sqrtf(s1), 1e-12f);
  #pragma unroll
  for (int d = 0; d < 16; ++d) { a0[d] /= dn0; a1[d] /= dn1; }

  float4* op0 = (float4*)znp + (size_t)n0 * 4;
  float4* op1 = (float4*)znp + (size_t)(n0 + 128) * 4;
  op0[0] = make_float4(a0[0],a0[1],a0[2],a0[3]);
  op0[1] = make_float4(a0[4],a0[5],a0[6],a0[7]);
  op0[2] = make_float4(a0[8],a0[9],a0[10],a0[11]);
  op0[3] = make_float4(a0[12],a0[13],a0[14],a0[15]);
  op1[0] = make_float4(a1[0],a1[1],a1[2],a1[3]);
  op1[1] = make_float4(a1[4],a1[5],a1[6],a1[7]);
  op1[2] = make_float4(a1[8],a1[9],a1[10],a1[11]);
  op1[3] = make_float4(a1[12],a1[13],a1[14],a1[15]);
}

// ============ argmin scan: K split 16 ways, 8 tokens/thread ============
// score = enn - 2*dot  (znn constant per token -> argmin-equal)
__global__ __launch_bounds__(256, 2) void kscan_kernel(const float* __restrict__ enorm,
                                                       const float* __restrict__ ennp,
                                                       const float* __restrict__ znp,
                                                       unsigned long long* __restrict__ packp) {
  __shared__ float ecache[CPS * DDIM]; // 16 KB
  __shared__ float encache[CPS];       // 1 KB

  const int tid = threadIdx.x;
  const int kbase = blockIdx.y * CPS;

  {
    const float4* s4 = (const float4*)(enorm + (size_t)kbase * 16);
    float4* d4 = (float4*)ecache;
    #pragma unroll
    for (int i = 0; i < 4; ++i) d4[tid + i * 256] = s4[tid + i * 256];
    encache[tid] = ennp[kbase + tid];
  }
  __syncthreads();

  float nz[TPT][16];
  float best[TPT];
  int bidx[TPT];
  const int tokbase = blockIdx.x * TBLK + tid;
  {
    const float4* zp = (const float4*)znp;
    #pragma unroll
    for (int p = 0; p < TPT; ++p) {
      int tok = tokbase + p * 256;
      float4 a0 = zp[(size_t)tok * 4 + 0];
      float4 a1 = zp[(size_t)tok * 4 + 1];
      float4 a2 = zp[(size_t)tok * 4 + 2];
      float4 a3 = zp[(size_t)tok * 4 + 3];
      nz[p][0]=-2.f*a0.x; nz[p][1]=-2.f*a0.y; nz[p][2]=-2.f*a0.z; nz[p][3]=-2.f*a0.w;
      nz[p][4]=-2.f*a1.x; nz[p][5]=-2.f*a1.y; nz[p][6]=-2.f*a1.z; nz[p][7]=-2.f*a1.w;
      nz[p][8]=-2.f*a2.x; nz[p][9]=-2.f*a2.y; nz[p][10]=-2.f*a2.z; nz[p][11]=-2.f*a2.w;
      nz[p][12]=-2.f*a3.x; nz[p][13]=-2.f*a3.y; nz[p][14]=-2.f*a3.z; nz[p][15]=-2.f*a3.w;
      best[p] = 3.4e38f;
      bidx[p] = 0;
    }
  }

  #pragma unroll 2
  for (int j = 0; j < CPS; ++j) {
    const float4* e4 = (const float4*)(ecache + j * 16);
    float4 c0 = e4[0], c1 = e4[1], c2 = e4[2], c3 = e4[3];
    float en = encache[j];
    #pragma unroll
    for (int p = 0; p < TPT; ++p) {
      float d = en;
      d = fmaf(nz[p][0],  c0.x, d); d = fmaf(nz[p][1],  c0.y, d);
      d = fmaf(nz[p][2],  c0.z, d); d = fmaf(nz[p][3],  c0.w, d);
      d = fmaf(nz[p][4],  c1.x, d); d = fmaf(nz[p][5],  c1.y, d);
      d = fmaf(nz[p][6],  c1.z, d); d = fmaf(nz[p][7],  c1.w, d);
      d = fmaf(nz[p][8],  c2.x, d); d = fmaf(nz[p][9],  c2.y, d);
      d = fmaf(nz[p][10], c2.z, d); d = fmaf(nz[p][11], c2.w, d);
      d = fmaf(nz[p][12], c3.x, d); d = fmaf(nz[p][13], c3.y, d);
      d = fmaf(nz[p][14], c3.z, d); d = fmaf(nz[p][15], c3.w, d);
      if (d < best[p]) { best[p] = d; bidx[p] = j; }
    }
  }

  #pragma unroll
  for (int p = 0; p < TPT; ++p) {
    int tok = tokbase + p * 256;
    unsigned u = __float_as_uint(best[p]);
    u = (u & 0x80000000u) ? ~u : (u | 0x80000000u);
    unsigned long long key =
        ((unsigned long long)u << 32) | (unsigned)(kbase + bidx[p]);
    atomicMin(packp + tok, key);
  }
}

// ============ merge + scatter + loss + fused up-proj, 2 tokens/thread ============
__global__ __launch_bounds__(128, 2) void kfinal_kernel(const float* __restrict__ w_up,
                                                        const float* __restrict__ b_up,
                                                        const float* __restrict__ enorm,
                                                        const float* __restrict__ znp,
                                                        const unsigned long long* __restrict__ packp,
                                                        float* __restrict__ wsacc,
                                                        float* __restrict__ out) {
  __shared__ float wu[CDIM * DDIM]; // 16 KB
  __shared__ float bu[CDIM];
  const int tid = threadIdx.x;
  {
    const float4* s4 = (const float4*)w_up;
    float4* d4 = (float4*)wu;
    #pragma unroll
    for (int i = 0; i < 8; ++i) d4[tid + i * 128] = s4[tid + i * 128];
    bu[tid] = b_up[tid];
    bu[tid + 128] = b_up[tid + 128];
  }
  __syncthreads();

  const int n0 = blockIdx.x * 256 + tid; // second token = n0 + 128
  float ls = 0.f;
  float ql0[16], ql1[16];

  #pragma unroll
  for (int t = 0; t < 2; ++t) {
    const int n = n0 + t * 128;
    const int bidx = (int)(unsigned)(packp[n] & 0xFFFFFFFFull);
    float zn[16], zq[16];
    {
      const float4* zp = (const float4*)znp + (size_t)n * 4;
      float4 a0 = zp[0], a1 = zp[1], a2 = zp[2], a3 = zp[3];
      zn[0]=a0.x; zn[1]=a0.y; zn[2]=a0.z; zn[3]=a0.w;
      zn[4]=a1.x; zn[5]=a1.y; zn[6]=a1.z; zn[7]=a1.w;
      zn[8]=a2.x; zn[9]=a2.y; zn[10]=a2.z; zn[11]=a2.w;
      zn[12]=a3.x; zn[13]=a3.y; zn[14]=a3.z; zn[15]=a3.w;
    }
    {
      const float4* eb = (const float4*)enorm + (size_t)bidx * 4;
      float4 q0 = eb[0], q1 = eb[1], q2 = eb[2], q3 = eb[3];
      zq[0]=q0.x; zq[1]=q0.y; zq[2]=q0.z; zq[3]=q0.w;
      zq[4]=q1.x; zq[5]=q1.y; zq[6]=q1.z; zq[7]=q1.w;
      zq[8]=q2.x; zq[9]=q2.y; zq[10]=q2.z; zq[11]=q2.w;
      zq[12]=q3.x; zq[13]=q3.y; zq[14]=q3.z; zq[15]=q3.w;
    }
    out[OFS_IDX + n] = (float)bidx;
    #pragma unroll
    for (int d = 0; d < 16; ++d) { float df = zn[d] - zq[d]; ls = fmaf(df, df, ls); }
    atomicAdd(wsacc + bidx, 1.0f);
    #pragma unroll
    for (int d = 0; d < 16; ++d)
      atomicAdd(wsacc + KCOD + (size_t)bidx * 16 + d, zn[d]);
    float* ql = t ? ql1 : ql0;
    #pragma unroll
    for (int d = 0; d < 16; ++d) ql[d] = zn[d] + (zq[d] - zn[d]);
  }

  #pragma unroll
  for (int off = 32; off > 0; off >>= 1) ls += __shfl_down(ls, off, 64);
  if ((tid & 63) == 0) atomicAdd(wsacc + KCOD + KCOD * DDIM + 0, ls); // SCAL[0]

  const int b = n0 >> 12, hw = n0 & 4095;
  float* op = out + OFS_ZQ + (size_t)b * (CDIM * HWSZ) + hw;
  #pragma unroll 8
  for (int c = 0; c < CDIM; ++c) {
    const float4* wr = (const float4*)(wu + c * 16);
    float4 w0 = wr[0], w1 = wr[1], w2 = wr[2], w3 = wr[3];
    float a = 0.f, a2 = 0.f;
    a  = fmaf(ql0[0],  w0.x, a);  a2 = fmaf(ql1[0],  w0.x, a2);
    a  = fmaf(ql0[1],  w0.y, a);  a2 = fmaf(ql1[1],  w0.y, a2);
    a  = fmaf(ql0[2],  w0.z, a);  a2 = fmaf(ql1[2],  w0.z, a2);
    a  = fmaf(ql0[3],  w0.w, a);  a2 = fmaf(ql1[3],  w0.w, a2);
    a  = fmaf(ql0[4],  w1.x, a);  a2 = fmaf(ql1[4],  w1.x, a2);
    a  = fmaf(ql0[5],  w1.y, a);  a2 = fmaf(ql1[5],  w1.y, a2);
    a  = fmaf(ql0[6],  w1.z, a);  a2 = fmaf(ql1[6],  w1.z, a2);
    a  = fmaf(ql0[7],  w1.w, a);  a2 = fmaf(ql1[7],  w1.w, a2);
    a  = fmaf(ql0[8],  w2.x, a);  a2 = fmaf(ql1[8],  w2.x, a2);
    a  = fmaf(ql0[9],  w2.y, a);  a2 = fmaf(ql1[9],  w2.y, a2);
    a  = fmaf(ql0[10], w2.z, a);  a2 = fmaf(ql1[10], w2.z, a2);
    a  = fmaf(ql0[11], w2.w, a);  a2 = fmaf(ql1[11], w2.w, a2);
    a  = fmaf(ql0[12], w3.x, a);  a2 = fmaf(ql1[12], w3.x, a2);
    a  = fmaf(ql0[13], w3.y, a);  a2 = fmaf(ql1[13], w3.y, a2);
    a  = fmaf(ql0[14], w3.z, a);  a2 = fmaf(ql1[14], w3.z, a2);
    a  = fmaf(ql0[15], w3.w, a);  a2 = fmaf(ql1[15], w3.w, a2);
    op[(size_t)c * HWSZ] = a + bu[c];
    op[(size_t)c * HWSZ + 128] = a2 + bu[c];
  }
}

// ============ EMA buffers + partial sums (n, entropy) ============
__global__ __launch_bounds__(256) void kema_kernel(const float* __restrict__ cluster_size,
                                                   const float* __restrict__ embed_avg,
                                                   float* __restrict__ ws,
                                                   float* __restrict__ out) {
  const float DEC = 0.99f;
  const float OMD = (float)(1.0 - 0.99);
  const int k = blockIdx.x * 256 + threadIdx.x;
  float bcsv = ws[WS_BCS + k];
  float ncs = cluster_size[k] * DEC + OMD * bcsv;
  out[OFS_NCS + k] = ncs;
  #pragma unroll
  for (int d = 0; d < 16; ++d) {
    float nea = embed_avg[(size_t)k * 16 + d] * DEC + OMD * ws[WS_BES + (size_t)k * 16 + d];
    out[OFS_NEA + (size_t)k * 16 + d] = nea;
  }
  float p = bcsv / 65536.0f;
  float et = -p * logf(p + 1e-8f);

  __shared__ float r1[4], r2[4];
  float v1 = ncs, v2 = et;
  #pragma unroll
  for (int off = 32; off > 0; off >>= 1) {
    v1 += __shfl_down(v1, off, 64);
    v2 += __shfl_down(v2, off, 64);
  }
  int lane = threadIdx.x & 63, w = threadIdx.x >> 6;
  if (lane == 0) { r1[w] = v1; r2[w] = v2; }
  __syncthreads();
  if (threadIdx.x == 0) {
    atomicAdd(ws + WS_SCAL + 1, (r1[0] + r1[1]) + (r1[2] + r1[3]));
    atomicAdd(ws + WS_SCAL + 2, (r2[0] + r2[1]) + (r2[2] + r2[3]));
  }
}

// ============ new_embedding + scalar outputs ============
__global__ __launch_bounds__(256) void kemb_kernel(const float* __restrict__ ws,
                                                   float* __restrict__ out) {
  const float KEPS = (float)(4096.0 * 1e-5);
  const int k = blockIdx.x * 256 + threadIdx.x;
  float n = ws[WS_SCAL + 1];
  float ncs = out[OFS_NCS + k];
  float cs = (ncs + 1e-5f) / (n + KEPS) * n;
  #pragma unroll
  for (int d = 0; d < 16; ++d)
    out[OFS_NE + (size_t)k * 16 + d] = out[OFS_NEA + (size_t)k * 16 + d] / cs;
  if (k == 0) {
    out[OFS_LOSS] = 0.25f * (ws[WS_SCAL + 0] / 1048576.0f);
    out[OFS_ENT]  = (float)8.317766166719343 - ws[WS_SCAL + 2];
  }
}

extern "C" void kernel_launch(void* const* d_in, const int* in_sizes, int n_in,
                              void* d_out, int out_size, void* d_ws, size_t ws_size,
                              hipStream_t stream) {
  const float* z        = (const float*)d_in[0];
  const float* w_down   = (const float*)d_in[1];
  const float* b_down   = (const float*)d_in[2];
  const float* w_up     = (const float*)d_in[3];
  const float* b_up     = (const float*)d_in[4];
  const float* emb      = (const float*)d_in[5];
  const float* csz      = (const float*)d_in[6];
  const float* eavg     = (const float*)d_in[7];
  float* out = (float*)d_out;
  float* ws  = (float*)d_ws;

  hipMemsetAsync(ws + WS_BCS, 0, (size_t)(KCOD + KCOD*DDIM + 8) * sizeof(float), stream);
  hipMemsetAsync(ws + WS_PACK, 0xFF, (size_t)NTOK * 8, stream);

  knorm_kernel<<<KCOD / 256, 256, 0, stream>>>(emb, w_down, ws);
  kdown_kernel<<<NTOK / 256, 128, 0, stream>>>(z, ws + WS_WDT, b_down, ws + WS_ZN);
  kscan_kernel<<<dim3(NTOK / TBLK, KSPLIT), 256, 0, stream>>>(
      ws + WS_ENORM, ws + WS_ENN, ws + WS_ZN,
      (unsigned long long*)(ws + WS_PACK));
  kfinal_kernel<<<NTOK / 256, 128, 0, stream>>>(
      w_up, b_up, ws + WS_ENORM, ws + WS_ZN,
      (const unsigned long long*)(ws + WS_PACK), ws + WS_BCS, out);
  kema_kernel<<<KCOD / 256, 256, 0, stream>>>(csz, eavg, ws, out);
  kemb_kernel<<<KCOD / 256, 256, 0, stream>>>(ws, out);
}